// Round 9
// baseline (536.686 us; speedup 1.0000x reference)
//
#include <hip/hip_runtime.h>
#include <hip/hip_bf16.h>

typedef __hip_bfloat16 bf16;
typedef __attribute__((ext_vector_type(8))) short bf16x8;   // x32 MFMA A/B frag (4 VGPRs)
typedef __attribute__((ext_vector_type(4))) short bf16x4;   // x16 MFMA A/B frag (2 VGPRs)
typedef __attribute__((ext_vector_type(4))) float f32x4;    // MFMA C/D frag

// Problem constants (Attention_45681272160684)
#define BATCH 2
#define SEQ 2048
#define CDIM 2048
#define NH 16
#define NKV 4
#define HD 128
#define NQKV 3072   // fused projection width: 2048 Q | 512 K | 512 V

__device__ __forceinline__ float tof(float x)  { return x; }
__device__ __forceinline__ float tof(bf16 x)   { return __bfloat162float(x); }
__device__ __forceinline__ void  stf(float* p, float v) { *p = v; }
__device__ __forceinline__ void  stf(bf16* p,  float v) { *p = __float2bfloat16(v); }

__device__ __forceinline__ float bfs2f(short s) {
    union { unsigned u; float f; } v; v.u = ((unsigned)(unsigned short)s) << 16; return v.f;
}
__device__ __forceinline__ short f2bfs(float f) {
    bf16 h = __float2bfloat16(f);
    return *reinterpret_cast<short*>(&h);
}

__device__ __forceinline__ void gl_lds16(const bf16* g, bf16* l) {
    typedef const __attribute__((address_space(1))) unsigned int* gp_t;
    typedef __attribute__((address_space(3))) unsigned int* lp_t;
    __builtin_amdgcn_global_load_lds((gp_t)g, (lp_t)l, 16, 0, 0);
}

__device__ __forceinline__ f32x4 mfma16x16x16_bf16(bf16x4 a, bf16x4 b, f32x4 c) {
#if __has_builtin(__builtin_amdgcn_mfma_f32_16x16x16bf16_1k)
    return __builtin_amdgcn_mfma_f32_16x16x16bf16_1k(a, b, c, 0, 0, 0);
#else
    asm volatile("v_mfma_f32_16x16x16_bf16 %0, %1, %2, %0"
                 : "+v"(c) : "v"(a), "v"(b));
    return c;
#endif
}

__device__ __forceinline__ float fast_exp2(float x) {
#if __has_builtin(__builtin_amdgcn_exp2f)
    return __builtin_amdgcn_exp2f(x);
#else
    return exp2f(x);
#endif
}

// ---------------------------------------------------------------------------
// fp32 -> bf16 convert
// ---------------------------------------------------------------------------
__global__ __launch_bounds__(256) void f2b_kernel(const float* __restrict__ in,
                                                  bf16* __restrict__ out, int n4)
{
    int i = blockIdx.x * 256 + threadIdx.x;
    if (i >= n4) return;
    float4 v = *(const float4*)&in[(size_t)i * 4];
    bf16 o[4] = {__float2bfloat16(v.x), __float2bfloat16(v.y),
                 __float2bfloat16(v.z), __float2bfloat16(v.w)};
    *(ushort4*)&out[(size_t)i * 4] = *(ushort4*)o;
}

// ---------------------------------------------------------------------------
// Transposing convert: fp32 [R, Cn] -> bf16 [Cn, R]
// ---------------------------------------------------------------------------
__global__ __launch_bounds__(256) void transpose_f2b_kernel(
    const float* __restrict__ in, bf16* __restrict__ out, int R, int Cn)
{
    __shared__ float tile[64][65];
    const int r0 = blockIdx.y * 64, c0 = blockIdx.x * 64;
    for (int f = threadIdx.x; f < 4096; f += 256) {
        int r = f >> 6, c = f & 63;
        tile[r][c] = in[(size_t)(r0 + r) * Cn + c0 + c];
    }
    __syncthreads();
    for (int f = threadIdx.x; f < 4096; f += 256) {
        int r = f >> 6, c = f & 63;
        out[(size_t)(c0 + r) * R + r0 + c] = __float2bfloat16(tile[c][r]);
    }
}

// ---------------------------------------------------------------------------
// bf16 transpose of V columns of XQKV (cols 2560..3071, row stride 3072):
// -> Vt_g [(b*NKV+kvh)*HD + d][SEQ].  grid (512/64, SEQ/64, B)
// ---------------------------------------------------------------------------
__global__ __launch_bounds__(256) void vtrans_kernel(
    const bf16* __restrict__ in, bf16* __restrict__ out)
{
    __shared__ bf16 tile[64][65];
    const int b = blockIdx.z;
    const int t0 = blockIdx.y * 64, c0 = blockIdx.x * 64;
    for (int f = threadIdx.x; f < 4096; f += 256) {
        int r = f >> 6, c = f & 63;
        tile[r][c] = in[(size_t)(b * SEQ + t0 + r) * NQKV + 2560 + c0 + c];
    }
    __syncthreads();
    for (int f = threadIdx.x; f < 4096; f += 256) {
        int r = f >> 6, c = f & 63;
        out[(size_t)(b * NKV * HD + c0 + r) * SEQ + t0 + c] = tile[c][r];
    }
}

// ---------------------------------------------------------------------------
// MFMA GEMM: C[M,N] = A[M,K] @ Bt[N,K]^T (m97 structure) — unchanged, passing.
// ---------------------------------------------------------------------------
template <typename TC>
__global__ __launch_bounds__(256) void gemm_mfma_bt(
    const bf16* __restrict__ A, const bf16* __restrict__ Bt, TC* __restrict__ C,
    int M, int N, int K)
{
    __shared__ __align__(16) bf16 As[128 * 32];
    __shared__ __align__(16) bf16 Bs[128 * 32];

    const int tid = threadIdx.x;
    const int lane = tid & 63;
    const int wave = tid >> 6;
    const int m0 = blockIdx.y * 128;
    const int n0 = blockIdx.x * 128;
    const int wm = (wave >> 1) * 64;
    const int wn = (wave & 1) * 64;
    const int quad = lane >> 4;
    const int l16 = lane & 15;

    const int srow = tid >> 2;
    const int scol = (tid & 3) * 8;
    const bf16* Ag0 = A  + (size_t)(m0 + srow) * K + scol;
    const bf16* Ag1 = A  + (size_t)(m0 + srow + 64) * K + scol;
    const bf16* Bg0 = Bt + (size_t)(n0 + srow) * K + scol;
    const bf16* Bg1 = Bt + (size_t)(n0 + srow + 64) * K + scol;

    f32x4 acc[4][4];
#pragma unroll
    for (int mi = 0; mi < 4; ++mi)
#pragma unroll
        for (int ni = 0; ni < 4; ++ni)
            acc[mi][ni] = (f32x4){0.f, 0.f, 0.f, 0.f};

    for (int kt = 0; kt < K; kt += 32) {
        __syncthreads();
        gl_lds16(Ag0 + kt, &As[tid * 8]);
        gl_lds16(Ag1 + kt, &As[2048 + tid * 8]);
        gl_lds16(Bg0 + kt, &Bs[tid * 8]);
        gl_lds16(Bg1 + kt, &Bs[2048 + tid * 8]);
        __syncthreads();

        bf16x8 a[4], b[4];
#pragma unroll
        for (int mi = 0; mi < 4; ++mi)
            a[mi] = *(const bf16x8*)&As[(wm + mi * 16 + l16) * 32 + quad * 8];
#pragma unroll
        for (int ni = 0; ni < 4; ++ni)
            b[ni] = *(const bf16x8*)&Bs[(wn + ni * 16 + l16) * 32 + quad * 8];
#pragma unroll
        for (int mi = 0; mi < 4; ++mi)
#pragma unroll
            for (int ni = 0; ni < 4; ++ni)
                acc[mi][ni] = __builtin_amdgcn_mfma_f32_16x16x32_bf16(
                    a[mi], b[ni], acc[mi][ni], 0, 0, 0);
    }

#pragma unroll
    for (int mi = 0; mi < 4; ++mi)
#pragma unroll
        for (int ni = 0; ni < 4; ++ni) {
            int col = n0 + wn + ni * 16 + l16;
#pragma unroll
            for (int r = 0; r < 4; ++r) {
                int row = m0 + wm + mi * 16 + quad * 4 + r;
                stf(&C[(size_t)row * N + col], acc[mi][ni][r]);
            }
        }
}

// ---------------------------------------------------------------------------
// RoPE on K columns of XQKV (in place): data points at XQKV + 2048.
// 256 pairs per row (4 heads x 64). total_pairs = rows * 256.
// ---------------------------------------------------------------------------
__global__ __launch_bounds__(256) void ropek_kernel(bf16* __restrict__ data,
                                                    int total_pairs)
{
    int idx = blockIdx.x * 256 + threadIdx.x;
    if (idx >= total_pairs) return;
    int row = idx >> 8;
    int p = idx & 255;
    int head = p >> 6;
    int i = p & 63;
    int t = row & (SEQ - 1);
    float inv_ts = expf(-(float)i * 0.14391156831212787f);   // 10000^(-i/64)
    float angle = (float)t * inv_ts;
    float s, c;
    sincosf(angle, &s, &c);
    size_t base = (size_t)row * NQKV + head * 128 + i;
    float x1 = __bfloat162float(data[base]);
    float x2 = __bfloat162float(data[base + 64]);
    data[base]      = __float2bfloat16(x1 * c - x2 * s);
    data[base + 64] = __float2bfloat16(x2 * c + x1 * s);
}

// ---------------------------------------------------------------------------
// LDS-staged register-transpose MFMA flash attention (validated R8 core),
// reading Q/K as strided views of fused XQKV (row stride 3072), with Q-RoPE
// fused in-register (pair d,d+64 lives in frags kk,kk+2 of the same lane).
// ---------------------------------------------------------------------------
__global__ __launch_bounds__(256, 4) void attn_mfma4_kernel(
    const bf16* __restrict__ XQKV, const bf16* __restrict__ Vt,
    bf16* __restrict__ Att)
{
    __shared__ __align__(16) char smem[34816];       // Ks 16K | Vts 16K, reused as CB
    bf16* Ks  = (bf16*)smem;                         // [64 key][128 d] 16B-chunk-swizzled
    bf16* Vts = (bf16*)(smem + 16384);               // [128 d][64 key] 16B-chunk-swizzled
    float* CB = (float*)smem;                        // combine overlay (34816 B)
    __shared__ float lbuf[2][2][16];                 // [qw][g][l16] partial l from kw=0

    const int tid = threadIdx.x;
    const int lane = tid & 63;
    const int w = tid >> 6;
    const int kw = w >> 1;            // key half (0: keys 0-31, 1: 32-63 of tile)
    const int qw = w & 1;             // q half (32 q each)
    const int quad = lane >> 4;
    const int l16 = lane & 15;
    const int bh = blockIdx.y;
    const int b = bh >> 4;
    const int hq = bh & 15;
    const int kvh = hq & 3;
    const int qt = (gridDim.x - 1) - blockIdx.x;     // heavy-first
    const int q0 = qt * 64 + qw * 32;                // wave's q rows: q0 + g*16 + l16

    // Q^T B-frags (x32) from XQKV cols hq*128.., row stride NQKV
    bf16x8 qf[2][4];
#pragma unroll
    for (int g = 0; g < 2; ++g) {
        size_t qrow = (size_t)(b * SEQ + q0 + g * 16 + l16) * NQKV + hq * HD;
#pragma unroll
        for (int kk = 0; kk < 4; ++kk)
            qf[g][kk] = *(const bf16x8*)&XQKV[qrow + kk * 32 + quad * 8];
    }
    // fused Q-RoPE: element d = kk*32+quad*8+j pairs with d+64 in frag kk+2
#pragma unroll
    for (int g = 0; g < 2; ++g) {
        float tq = (float)(q0 + g * 16 + l16);
#pragma unroll
        for (int kk = 0; kk < 2; ++kk)
#pragma unroll
            for (int j = 0; j < 8; ++j) {
                int i = kk * 32 + quad * 8 + j;
                float ang = tq * exp2f((float)i * -0.20762050593046014f);
                float sn, cs;
                sincosf(ang, &sn, &cs);
                float x1 = bfs2f(qf[g][kk][j]);
                float x2 = bfs2f(qf[g][kk + 2][j]);
                qf[g][kk][j]     = f2bfs(x1 * cs - x2 * sn);
                qf[g][kk + 2][j] = f2bfs(x2 * cs + x1 * sn);
            }
    }

    const bf16* Kb = XQKV + (size_t)(b * SEQ) * NQKV + 2048 + kvh * HD;  // row NQKV
    const bf16* Vb = Vt + (size_t)((b * NKV + kvh) * HD) * SEQ;          // row SEQ

    f32x4 O[2][8];   // O^T partial (this wave's key half): row=d=dj*16+quad*4+r, col=q
#pragma unroll
    for (int g = 0; g < 2; ++g)
#pragma unroll
        for (int dj = 0; dj < 8; ++dj) O[g][dj] = (f32x4){0.f, 0.f, 0.f, 0.f};
    float lsum[2] = {0.f, 0.f};

    // staging index precompute (linear-in-tid LDS dest; XOR swizzle in source)
    const int srowK = tid >> 4;                 // key-within-16-group
    const int sgcK  = (tid & 15) ^ srowK;       // swizzled d-chunk
    const int srowV = tid >> 3;                 // d-within-32-group
    const int sgcV  = (tid & 7) ^ (srowV & 7);  // swizzled key-chunk

    const int ntiles = qt + 1;
    for (int jt = 0; jt < ntiles; ++jt) {
        const int j0 = jt * 64;
        __syncthreads();   // previous tile's readers done
#pragma unroll
        for (int c = 0; c < 4; ++c) {
            gl_lds16(Kb + (size_t)(j0 + c * 16 + srowK) * NQKV + sgcK * 8,
                     Ks + c * 2048 + tid * 8);
            gl_lds16(Vb + (size_t)(c * 32 + srowV) * SEQ + j0 + sgcV * 8,
                     Vts + c * 2048 + tid * 8);
        }
        __syncthreads();   // vmcnt drained, tiles visible

        // ---- S^T[32 key][32 q]: A=K frags (swizzle-read), B=Q^T regs ----
        f32x4 sacc[2][2];
#pragma unroll
        for (int mt = 0; mt < 2; ++mt) {
#pragma unroll
            for (int g = 0; g < 2; ++g) sacc[mt][g] = (f32x4){0.f, 0.f, 0.f, 0.f};
            const int krow = (kw * 32 + mt * 16 + l16) * 128;
#pragma unroll
            for (int kk = 0; kk < 4; ++kk) {
                bf16x8 kf = *(const bf16x8*)&Ks[krow + (((kk * 4 + quad) ^ l16) * 8)];
#pragma unroll
                for (int g = 0; g < 2; ++g)
                    sacc[mt][g] = __builtin_amdgcn_mfma_f32_16x16x32_bf16(
                        kf, qf[g][kk], sacc[mt][g], 0, 0, 0);
            }
        }

        // ---- softcap (Pade, exp2-folded) + mask -> P^T frags (registers) ----
        const bool diag = (jt == qt);
        bf16x4 pf[2][2];
#pragma unroll
        for (int mt = 0; mt < 2; ++mt)
#pragma unroll
            for (int g = 0; g < 2; ++g) {
                bf16 pb[4];
#pragma unroll
                for (int r = 0; r < 4; ++r) {
                    float u = sacc[mt][g][r];
                    float t2 = u * u;
                    float num = fmaf(t2, 9.96274e-4f, 8607.814f);
                    float den = fmaf(t2, 0.0703125f, 67500.f);
                    float s2 = u * num * __builtin_amdgcn_rcpf(den);
                    float p = fast_exp2(s2);     // exp(50*tanh(u/(sqrt(128)*50)))
                    if (diag) {
                        int kl = kw * 32 + mt * 16 + quad * 4 + r;
                        int ql = qw * 32 + g * 16 + l16;
                        p = (kl <= ql) ? p : 0.f;
                    }
                    lsum[g] += p;
                    pb[r] = __float2bfloat16(p);
                }
                pf[mt][g] = *(bf16x4*)pb;
            }

        // ---- O^T += V^T @ P^T (x16; V^T frags from swizzled LDS) ----
#pragma unroll
        for (int dj = 0; dj < 8; ++dj) {
            const int vrow = (dj * 16 + l16) * 64;
            const int dl7 = l16 & 7;
#pragma unroll
            for (int mt = 0; mt < 2; ++mt) {
                int c16 = kw * 4 + mt * 2 + (quad >> 1);
                bf16x4 vf = *(const bf16x4*)&Vts[vrow + ((c16 ^ dl7) << 3)
                                                 + (quad & 1) * 4];
#pragma unroll
                for (int g = 0; g < 2; ++g)
                    O[g][dj] = mfma16x16x16_bf16(vf, pf[mt][g], O[g][dj]);
            }
        }
    }

    // ---- combine key halves (no-max softmax: plain sums), normalize, store ----
    float lg[2];
#pragma unroll
    for (int g = 0; g < 2; ++g) {
        float v = lsum[g];
        v += __shfl_xor(v, 16);
        v += __shfl_xor(v, 32);
        lg[g] = v;                    // wave-total l for column (g, l16)
    }
    __syncthreads();                  // staging area free -> reuse as CB
    if (kw == 0) {
#pragma unroll
        for (int g = 0; g < 2; ++g) {
#pragma unroll
            for (int dj = 0; dj < 8; ++dj) {
                int basei = ((qw * 2 + g) * 8 + dj) * 272;
#pragma unroll
                for (int r = 0; r < 4; ++r)
                    CB[basei + (quad * 4 + r) * 17 + l16] = O[g][dj][r];
            }
            if (quad == 0) lbuf[qw][g][l16] = lg[g];
        }
    }
    __syncthreads();
    if (kw == 1) {
#pragma unroll
        for (int g = 0; g < 2; ++g) {
            float inv = 1.f / (lg[g] + lbuf[qw][g][l16]);
            size_t obase = (size_t)(b * SEQ + q0 + g * 16 + l16) * (NH * HD) + hq * HD;
#pragma unroll
            for (int dj = 0; dj < 8; ++dj) {
                int basei = ((qw * 2 + g) * 8 + dj) * 272;
                bf16 ob[4];
#pragma unroll
                for (int r = 0; r < 4; ++r) {
                    float v = O[g][dj][r] + CB[basei + (quad * 4 + r) * 17 + l16];
                    ob[r] = __float2bfloat16(v * inv);
                }
                *(ushort4*)&Att[obase + dj * 16 + quad * 4] = *(ushort4*)ob;
            }
        }
    }
}

// ---------------------------------------------------------------------------
extern "C" void kernel_launch(void* const* d_in, const int* in_sizes, int n_in,
                              void* d_out, int out_size, void* d_ws, size_t ws_size,
                              hipStream_t stream) {
    const float* x        = (const float*)d_in[0];
    // d_in[1] = mask: deterministic causal tril -> not read
    const float* q_kernel = (const float*)d_in[2];
    const float* k_kernel = (const float*)d_in[3];
    const float* v_kernel = (const float*)d_in[4];
    const float* o_kernel = (const float*)d_in[5];
    float* out = (float*)d_out;

    const int M = BATCH * SEQ;       // 4096
    // workspace (54.5 MB, same footprint as R8):
    //   [0,16M)        xb [4096,2048]; aliased by Att after QKV GEMM
    //   [16M,28M)      wT_qkv [3072,2048]; after QKV GEMM aliased by
    //                  woT [2048,2048] (8MB) + Vt_g [1024,2048] (4MB)
    //   [28M,54.5M)    XQKV [4096,3072]
    char* ws = (char*)d_ws;
    bf16* xb    = (bf16*)ws;
    bf16* Att   = xb;
    bf16* wT    = (bf16*)(ws + 16777216);                // fused [3072][2048]
    bf16* wTq   = wT;                                    // rows 0..2047
    bf16* wTk   = wT + (size_t)2048 * 2048;              // rows 2048..2559
    bf16* wTv   = wT + (size_t)2560 * 2048;              // rows 2560..3071
    bf16* woT   = wT;                                    // alias after QKV GEMM
    bf16* Vt_g  = (bf16*)(ws + 16777216 + 8388608);      // alias after QKV GEMM
    bf16* XQKV  = (bf16*)(ws + 29360128);                // [4096][3072]

    f2b_kernel<<<(M * CDIM / 4 + 255) / 256, 256, 0, stream>>>(x, xb, M * CDIM / 4);
    transpose_f2b_kernel<<<dim3((NH * HD) / 64, CDIM / 64), 256, 0, stream>>>(
        q_kernel, wTq, CDIM, NH * HD);
    transpose_f2b_kernel<<<dim3((NKV * HD) / 64, CDIM / 64), 256, 0, stream>>>(
        k_kernel, wTk, CDIM, NKV * HD);
    transpose_f2b_kernel<<<dim3((NKV * HD) / 64, CDIM / 64), 256, 0, stream>>>(
        v_kernel, wTv, CDIM, NKV * HD);

    // fused QKV projection: [4096,2048] @ [3072,2048]^T -> XQKV (768 blocks)
    gemm_mfma_bt<bf16><<<dim3(NQKV / 128, M / 128), 256, 0, stream>>>(
        xb, wT, XQKV, M, NQKV, CDIM);

    // o_kernel transpose into woT (aliases wT -> must follow QKV GEMM)
    transpose_f2b_kernel<<<dim3(CDIM / 64, CDIM / 64), 256, 0, stream>>>(
        o_kernel, woT, CDIM, CDIM);

    // K-RoPE in place on XQKV K columns
    ropek_kernel<<<(M * 256) / 256, 256, 0, stream>>>(XQKV + 2048, M * 256);

    // V transpose (reads XQKV V cols; writes Vt_g region - after QKV GEMM)
    vtrans_kernel<<<dim3((NKV * HD) / 64, SEQ / 64, BATCH), 256, 0, stream>>>(
        XQKV, Vt_g);

    // flash attention (fused Q-RoPE): 64 q/block, grid (T/64, B*NH)
    attn_mfma4_kernel<<<dim3(SEQ / 64, BATCH * NH), 256, 0, stream>>>(
        XQKV, Vt_g, Att);

    // output projection
    gemm_mfma_bt<float><<<dim3(CDIM / 128, M / 128), 256, 0, stream>>>(
        Att, woT, out, M, CDIM, CDIM);
}

// Round 10
// 422.509 us; speedup vs baseline: 1.2702x; 1.2702x over previous
//
#include <hip/hip_runtime.h>
#include <hip/hip_bf16.h>

typedef __hip_bfloat16 bf16;
typedef __attribute__((ext_vector_type(8))) short bf16x8;   // x32 MFMA A/B frag (4 VGPRs)
typedef __attribute__((ext_vector_type(4))) short bf16x4;   // x16 MFMA A/B frag (2 VGPRs)
typedef __attribute__((ext_vector_type(4))) float f32x4;    // MFMA C/D frag

// Problem constants (Attention_45681272160684)
#define BATCH 2
#define SEQ 2048
#define CDIM 2048
#define NH 16
#define NKV 4
#define HD 128
#define NQKV 3072   // fused projection width: 2048 Q | 512 K | 512 V

__device__ __forceinline__ float tof(float x)  { return x; }
__device__ __forceinline__ float tof(bf16 x)   { return __bfloat162float(x); }
__device__ __forceinline__ void  stf(float* p, float v) { *p = v; }
__device__ __forceinline__ void  stf(bf16* p,  float v) { *p = __float2bfloat16(v); }

__device__ __forceinline__ void gl_lds16(const bf16* g, bf16* l) {
    typedef const __attribute__((address_space(1))) unsigned int* gp_t;
    typedef __attribute__((address_space(3))) unsigned int* lp_t;
    __builtin_amdgcn_global_load_lds((gp_t)g, (lp_t)l, 16, 0, 0);
}

__device__ __forceinline__ f32x4 mfma16x16x16_bf16(bf16x4 a, bf16x4 b, f32x4 c) {
#if __has_builtin(__builtin_amdgcn_mfma_f32_16x16x16bf16_1k)
    return __builtin_amdgcn_mfma_f32_16x16x16bf16_1k(a, b, c, 0, 0, 0);
#else
    asm volatile("v_mfma_f32_16x16x16_bf16 %0, %1, %2, %0"
                 : "+v"(c) : "v"(a), "v"(b));
    return c;
#endif
}

__device__ __forceinline__ float fast_exp2(float x) {
#if __has_builtin(__builtin_amdgcn_exp2f)
    return __builtin_amdgcn_exp2f(x);
#else
    return exp2f(x);
#endif
}

// ---------------------------------------------------------------------------
// fp32 -> bf16 convert
// ---------------------------------------------------------------------------
__global__ __launch_bounds__(256) void f2b_kernel(const float* __restrict__ in,
                                                  bf16* __restrict__ out, int n4)
{
    int i = blockIdx.x * 256 + threadIdx.x;
    if (i >= n4) return;
    float4 v = *(const float4*)&in[(size_t)i * 4];
    bf16 o[4] = {__float2bfloat16(v.x), __float2bfloat16(v.y),
                 __float2bfloat16(v.z), __float2bfloat16(v.w)};
    *(ushort4*)&out[(size_t)i * 4] = *(ushort4*)o;
}

// ---------------------------------------------------------------------------
// Transposing convert: fp32 [R, Cn] -> bf16 [Cn, R]
// ---------------------------------------------------------------------------
__global__ __launch_bounds__(256) void transpose_f2b_kernel(
    const float* __restrict__ in, bf16* __restrict__ out, int R, int Cn)
{
    __shared__ float tile[64][65];
    const int r0 = blockIdx.y * 64, c0 = blockIdx.x * 64;
    for (int f = threadIdx.x; f < 4096; f += 256) {
        int r = f >> 6, c = f & 63;
        tile[r][c] = in[(size_t)(r0 + r) * Cn + c0 + c];
    }
    __syncthreads();
    for (int f = threadIdx.x; f < 4096; f += 256) {
        int r = f >> 6, c = f & 63;
        out[(size_t)(c0 + r) * R + r0 + c] = __float2bfloat16(tile[c][r]);
    }
}

// ---------------------------------------------------------------------------
// bf16 transpose per batch: Vr [B*SEQ, NKV*HD] -> Vt_g [(b*NKV+kvh)*HD + d][SEQ]
// ---------------------------------------------------------------------------
__global__ __launch_bounds__(256) void vtrans_kernel(
    const bf16* __restrict__ in, bf16* __restrict__ out)
{
    __shared__ bf16 tile[64][65];
    const int b = blockIdx.z;
    const int t0 = blockIdx.y * 64, c0 = blockIdx.x * 64;
    for (int f = threadIdx.x; f < 4096; f += 256) {
        int r = f >> 6, c = f & 63;
        tile[r][c] = in[(size_t)(b * SEQ + t0 + r) * (NKV * HD) + c0 + c];
    }
    __syncthreads();
    for (int f = threadIdx.x; f < 4096; f += 256) {
        int r = f >> 6, c = f & 63;
        out[(size_t)(b * NKV * HD + c0 + r) * SEQ + t0 + c] = tile[c][r];
    }
}

// ---------------------------------------------------------------------------
// Fused QKV MFMA GEMM with segment-remap epilogue:
// [M,2048] @ wT[3072,2048]^T; cols 0..2047 -> Qr (stride 2048),
// 2048..2559 -> Kr (stride 512), 2560..3071 -> Vr (stride 512).
// Branch is uniform per block (n0 is a multiple of 128).
// ---------------------------------------------------------------------------
__global__ __launch_bounds__(256) void gemm_qkv_kernel(
    const bf16* __restrict__ A, const bf16* __restrict__ Bt,
    bf16* __restrict__ Qr, bf16* __restrict__ Kr, bf16* __restrict__ Vr,
    int M, int K)
{
    __shared__ __align__(16) bf16 As[128 * 32];
    __shared__ __align__(16) bf16 Bs[128 * 32];

    const int tid = threadIdx.x;
    const int lane = tid & 63;
    const int wave = tid >> 6;
    const int m0 = blockIdx.y * 128;
    const int n0 = blockIdx.x * 128;
    const int wm = (wave >> 1) * 64;
    const int wn = (wave & 1) * 64;
    const int quad = lane >> 4;
    const int l16 = lane & 15;

    const int srow = tid >> 2;
    const int scol = (tid & 3) * 8;
    const bf16* Ag0 = A  + (size_t)(m0 + srow) * K + scol;
    const bf16* Ag1 = A  + (size_t)(m0 + srow + 64) * K + scol;
    const bf16* Bg0 = Bt + (size_t)(n0 + srow) * K + scol;
    const bf16* Bg1 = Bt + (size_t)(n0 + srow + 64) * K + scol;

    f32x4 acc[4][4];
#pragma unroll
    for (int mi = 0; mi < 4; ++mi)
#pragma unroll
        for (int ni = 0; ni < 4; ++ni)
            acc[mi][ni] = (f32x4){0.f, 0.f, 0.f, 0.f};

    for (int kt = 0; kt < K; kt += 32) {
        __syncthreads();
        gl_lds16(Ag0 + kt, &As[tid * 8]);
        gl_lds16(Ag1 + kt, &As[2048 + tid * 8]);
        gl_lds16(Bg0 + kt, &Bs[tid * 8]);
        gl_lds16(Bg1 + kt, &Bs[2048 + tid * 8]);
        __syncthreads();

        bf16x8 a[4], b[4];
#pragma unroll
        for (int mi = 0; mi < 4; ++mi)
            a[mi] = *(const bf16x8*)&As[(wm + mi * 16 + l16) * 32 + quad * 8];
#pragma unroll
        for (int ni = 0; ni < 4; ++ni)
            b[ni] = *(const bf16x8*)&Bs[(wn + ni * 16 + l16) * 32 + quad * 8];
#pragma unroll
        for (int mi = 0; mi < 4; ++mi)
#pragma unroll
            for (int ni = 0; ni < 4; ++ni)
                acc[mi][ni] = __builtin_amdgcn_mfma_f32_16x16x32_bf16(
                    a[mi], b[ni], acc[mi][ni], 0, 0, 0);
    }

    // segment remap (block-uniform)
    bf16* Cp; int Nst, cbase;
    if (n0 < 2048)      { Cp = Qr; Nst = 2048; cbase = n0; }
    else if (n0 < 2560) { Cp = Kr; Nst = 512;  cbase = n0 - 2048; }
    else                { Cp = Vr; Nst = 512;  cbase = n0 - 2560; }

#pragma unroll
    for (int mi = 0; mi < 4; ++mi)
#pragma unroll
        for (int ni = 0; ni < 4; ++ni) {
            int col = cbase + wn + ni * 16 + l16;
#pragma unroll
            for (int r = 0; r < 4; ++r) {
                int row = m0 + wm + mi * 16 + quad * 4 + r;
                Cp[(size_t)row * Nst + col] = __float2bfloat16(acc[mi][ni][r]);
            }
        }
}

// ---------------------------------------------------------------------------
// MFMA GEMM: C[M,N] = A[M,K] @ Bt[N,K]^T (m97 structure) — out-projection.
// ---------------------------------------------------------------------------
template <typename TC>
__global__ __launch_bounds__(256) void gemm_mfma_bt(
    const bf16* __restrict__ A, const bf16* __restrict__ Bt, TC* __restrict__ C,
    int M, int N, int K)
{
    __shared__ __align__(16) bf16 As[128 * 32];
    __shared__ __align__(16) bf16 Bs[128 * 32];

    const int tid = threadIdx.x;
    const int lane = tid & 63;
    const int wave = tid >> 6;
    const int m0 = blockIdx.y * 128;
    const int n0 = blockIdx.x * 128;
    const int wm = (wave >> 1) * 64;
    const int wn = (wave & 1) * 64;
    const int quad = lane >> 4;
    const int l16 = lane & 15;

    const int srow = tid >> 2;
    const int scol = (tid & 3) * 8;
    const bf16* Ag0 = A  + (size_t)(m0 + srow) * K + scol;
    const bf16* Ag1 = A  + (size_t)(m0 + srow + 64) * K + scol;
    const bf16* Bg0 = Bt + (size_t)(n0 + srow) * K + scol;
    const bf16* Bg1 = Bt + (size_t)(n0 + srow + 64) * K + scol;

    f32x4 acc[4][4];
#pragma unroll
    for (int mi = 0; mi < 4; ++mi)
#pragma unroll
        for (int ni = 0; ni < 4; ++ni)
            acc[mi][ni] = (f32x4){0.f, 0.f, 0.f, 0.f};

    for (int kt = 0; kt < K; kt += 32) {
        __syncthreads();
        gl_lds16(Ag0 + kt, &As[tid * 8]);
        gl_lds16(Ag1 + kt, &As[2048 + tid * 8]);
        gl_lds16(Bg0 + kt, &Bs[tid * 8]);
        gl_lds16(Bg1 + kt, &Bs[2048 + tid * 8]);
        __syncthreads();

        bf16x8 a[4], b[4];
#pragma unroll
        for (int mi = 0; mi < 4; ++mi)
            a[mi] = *(const bf16x8*)&As[(wm + mi * 16 + l16) * 32 + quad * 8];
#pragma unroll
        for (int ni = 0; ni < 4; ++ni)
            b[ni] = *(const bf16x8*)&Bs[(wn + ni * 16 + l16) * 32 + quad * 8];
#pragma unroll
        for (int mi = 0; mi < 4; ++mi)
#pragma unroll
            for (int ni = 0; ni < 4; ++ni)
                acc[mi][ni] = __builtin_amdgcn_mfma_f32_16x16x32_bf16(
                    a[mi], b[ni], acc[mi][ni], 0, 0, 0);
    }

#pragma unroll
    for (int mi = 0; mi < 4; ++mi)
#pragma unroll
        for (int ni = 0; ni < 4; ++ni) {
            int col = n0 + wn + ni * 16 + l16;
#pragma unroll
            for (int r = 0; r < 4; ++r) {
                int row = m0 + wm + mi * 16 + quad * 4 + r;
                stf(&C[(size_t)row * N + col], acc[mi][ni][r]);
            }
        }
}

// ---------------------------------------------------------------------------
// RoPE in place on [rows, ncols] bf16
// ---------------------------------------------------------------------------
__global__ __launch_bounds__(256) void rope_kernel(bf16* __restrict__ data,
                                                   int ncols, int total_pairs)
{
    int idx = blockIdx.x * 256 + threadIdx.x;
    if (idx >= total_pairs) return;
    int half = ncols >> 1;
    int row = idx / half;
    int p = idx - row * half;
    int head = p >> 6;
    int i = p & 63;
    int t = row & (SEQ - 1);
    float inv_ts = expf(-(float)i * 0.14391156831212787f);
    float angle = (float)t * inv_ts;
    float s, c;
    sincosf(angle, &s, &c);
    size_t base = (size_t)row * ncols + head * 128 + i;
    float x1 = __bfloat162float(data[base]);
    float x2 = __bfloat162float(data[base + 64]);
    data[base]      = __float2bfloat16(x1 * c - x2 * s);
    data[base + 64] = __float2bfloat16(x2 * c + x1 * s);
}

// ---------------------------------------------------------------------------
// LDS-staged register-transpose MFMA flash attention (exact R8 core, 125 us).
// Block = 4 waves = (2 key-halves kw) x (2 q-halves qw); 64 q-rows/block,
// key tiles of 64. K + V^T staged via global_load_lds, XOR-swizzled.
//   S^T = x32 mfma(A=K, B=Q^T) -> C: row=key=quad*4+r, col=q=l16
//   P^T (= x16 B-frag layout) stays in registers; O^T += x16 mfma(V^T, P^T).
// No-max softmax (softcap |s|<=50) => key-split partials combine by plain sum.
// ---------------------------------------------------------------------------
__global__ __launch_bounds__(256, 3) void attn_mfma4_kernel(
    const bf16* __restrict__ Q, const bf16* __restrict__ K,
    const bf16* __restrict__ Vt, bf16* __restrict__ Att)
{
    __shared__ __align__(16) char smem[34816];       // Ks 16K | Vts 16K, reused as CB
    bf16* Ks  = (bf16*)smem;                         // [64 key][128 d] 16B-chunk-swizzled
    bf16* Vts = (bf16*)(smem + 16384);               // [128 d][64 key] 16B-chunk-swizzled
    float* CB = (float*)smem;                        // combine overlay (34816 B)
    __shared__ float lbuf[2][2][16];                 // [qw][g][l16] partial l from kw=0

    const int tid = threadIdx.x;
    const int lane = tid & 63;
    const int w = tid >> 6;
    const int kw = w >> 1;            // key half (0: keys 0-31, 1: 32-63 of tile)
    const int qw = w & 1;             // q half (32 q each)
    const int quad = lane >> 4;
    const int l16 = lane & 15;
    const int bh = blockIdx.y;
    const int b = bh >> 4;
    const int hq = bh & 15;
    const int kvh = hq & 3;
    const int qt = (gridDim.x - 1) - blockIdx.x;     // heavy-first
    const int q0 = qt * 64 + qw * 32;                // wave's q rows: q0 + g*16 + l16

    // Q^T B-frags (x32): two 16-q column groups
    bf16x8 qf[2][4];
#pragma unroll
    for (int g = 0; g < 2; ++g) {
        size_t qrow = (size_t)(b * SEQ + q0 + g * 16 + l16) * (NH * HD) + hq * HD;
#pragma unroll
        for (int kk = 0; kk < 4; ++kk)
            qf[g][kk] = *(const bf16x8*)&Q[qrow + kk * 32 + quad * 8];
    }

    const bf16* Kb = K  + (size_t)(b * SEQ) * (NKV * HD) + kvh * HD;  // row 512 elems
    const bf16* Vb = Vt + (size_t)((b * NKV + kvh) * HD) * SEQ;       // row 2048 elems

    f32x4 O[2][8];   // O^T partial (this wave's key half): row=d=dj*16+quad*4+r, col=q
#pragma unroll
    for (int g = 0; g < 2; ++g)
#pragma unroll
        for (int dj = 0; dj < 8; ++dj) O[g][dj] = (f32x4){0.f, 0.f, 0.f, 0.f};
    float lsum[2] = {0.f, 0.f};

    // staging index precompute (linear-in-tid LDS dest; XOR swizzle in source)
    const int srowK = tid >> 4;                 // key-within-16-group
    const int sgcK  = (tid & 15) ^ srowK;       // swizzled d-chunk
    const int srowV = tid >> 3;                 // d-within-32-group
    const int sgcV  = (tid & 7) ^ (srowV & 7);  // swizzled key-chunk

    const int ntiles = qt + 1;
    for (int jt = 0; jt < ntiles; ++jt) {
        const int j0 = jt * 64;
        __syncthreads();   // previous tile's readers done
#pragma unroll
        for (int c = 0; c < 4; ++c) {
            gl_lds16(Kb + (size_t)(j0 + c * 16 + srowK) * (NKV * HD) + sgcK * 8,
                     Ks + c * 2048 + tid * 8);
            gl_lds16(Vb + (size_t)(c * 32 + srowV) * SEQ + j0 + sgcV * 8,
                     Vts + c * 2048 + tid * 8);
        }
        __syncthreads();   // vmcnt drained, tiles visible

        // ---- S^T[32 key][32 q]: A=K frags (swizzle-read), B=Q^T regs ----
        f32x4 sacc[2][2];
#pragma unroll
        for (int mt = 0; mt < 2; ++mt) {
#pragma unroll
            for (int g = 0; g < 2; ++g) sacc[mt][g] = (f32x4){0.f, 0.f, 0.f, 0.f};
            const int krow = (kw * 32 + mt * 16 + l16) * 128;
#pragma unroll
            for (int kk = 0; kk < 4; ++kk) {
                bf16x8 kf = *(const bf16x8*)&Ks[krow + (((kk * 4 + quad) ^ l16) * 8)];
#pragma unroll
                for (int g = 0; g < 2; ++g)
                    sacc[mt][g] = __builtin_amdgcn_mfma_f32_16x16x32_bf16(
                        kf, qf[g][kk], sacc[mt][g], 0, 0, 0);
            }
        }

        // ---- softcap (Pade, exp2-folded) + mask -> P^T frags (registers) ----
        const bool diag = (jt == qt);
        bf16x4 pf[2][2];
#pragma unroll
        for (int mt = 0; mt < 2; ++mt)
#pragma unroll
            for (int g = 0; g < 2; ++g) {
                bf16 pb[4];
#pragma unroll
                for (int r = 0; r < 4; ++r) {
                    float u = sacc[mt][g][r];
                    float t2 = u * u;
                    float num = fmaf(t2, 9.96274e-4f, 8607.814f);
                    float den = fmaf(t2, 0.0703125f, 67500.f);
                    float s2 = u * num * __builtin_amdgcn_rcpf(den);
                    float p = fast_exp2(s2);     // exp(50*tanh(u/(sqrt(128)*50)))
                    if (diag) {
                        int kl = kw * 32 + mt * 16 + quad * 4 + r;
                        int ql = qw * 32 + g * 16 + l16;
                        p = (kl <= ql) ? p : 0.f;
                    }
                    lsum[g] += p;
                    pb[r] = __float2bfloat16(p);
                }
                pf[mt][g] = *(bf16x4*)pb;
            }

        // ---- O^T += V^T @ P^T (x16; V^T frags from swizzled LDS) ----
#pragma unroll
        for (int dj = 0; dj < 8; ++dj) {
            const int vrow = (dj * 16 + l16) * 64;
            const int dl7 = l16 & 7;
#pragma unroll
            for (int mt = 0; mt < 2; ++mt) {
                int c16 = kw * 4 + mt * 2 + (quad >> 1);
                bf16x4 vf = *(const bf16x4*)&Vts[vrow + ((c16 ^ dl7) << 3)
                                                 + (quad & 1) * 4];
#pragma unroll
                for (int g = 0; g < 2; ++g)
                    O[g][dj] = mfma16x16x16_bf16(vf, pf[mt][g], O[g][dj]);
            }
        }
    }

    // ---- combine key halves (no-max softmax: plain sums), normalize, store ----
    float lg[2];
#pragma unroll
    for (int g = 0; g < 2; ++g) {
        float v = lsum[g];
        v += __shfl_xor(v, 16);
        v += __shfl_xor(v, 32);
        lg[g] = v;                    // wave-total l for column (g, l16)
    }
    __syncthreads();                  // staging area free -> reuse as CB
    if (kw == 0) {
#pragma unroll
        for (int g = 0; g < 2; ++g) {
#pragma unroll
            for (int dj = 0; dj < 8; ++dj) {
                int basei = ((qw * 2 + g) * 8 + dj) * 272;
#pragma unroll
                for (int r = 0; r < 4; ++r)
                    CB[basei + (quad * 4 + r) * 17 + l16] = O[g][dj][r];
            }
            if (quad == 0) lbuf[qw][g][l16] = lg[g];
        }
    }
    __syncthreads();
    if (kw == 1) {
#pragma unroll
        for (int g = 0; g < 2; ++g) {
            float inv = 1.f / (lg[g] + lbuf[qw][g][l16]);
            size_t obase = (size_t)(b * SEQ + q0 + g * 16 + l16) * (NH * HD) + hq * HD;
#pragma unroll
            for (int dj = 0; dj < 8; ++dj) {
                int basei = ((qw * 2 + g) * 8 + dj) * 272;
                bf16 ob[4];
#pragma unroll
                for (int r = 0; r < 4; ++r) {
                    float v = O[g][dj][r] + CB[basei + (quad * 4 + r) * 17 + l16];
                    ob[r] = __float2bfloat16(v * inv);
                }
                *(ushort4*)&Att[obase + dj * 16 + quad * 4] = *(ushort4*)ob;
            }
        }
    }
}

// ---------------------------------------------------------------------------
extern "C" void kernel_launch(void* const* d_in, const int* in_sizes, int n_in,
                              void* d_out, int out_size, void* d_ws, size_t ws_size,
                              hipStream_t stream) {
    const float* x        = (const float*)d_in[0];
    // d_in[1] = mask: deterministic causal tril -> not read
    const float* q_kernel = (const float*)d_in[2];
    const float* k_kernel = (const float*)d_in[3];
    const float* v_kernel = (const float*)d_in[4];
    const float* o_kernel = (const float*)d_in[5];
    float* out = (float*)d_out;

    const int M = BATCH * SEQ;       // 4096
    // workspace (52 MB):
    //   [0,16M)    xb [4096,2048]; aliased by Att after QKV GEMM
    //   [16M,28M)  wT fused [3072][2048]; after QKV GEMM aliased by
    //              woT [2048,2048] (16M..24M) + Vt_g [1024,2048] (24M..28M)
    //   [28M,44M)  Qr [4096,2048]
    //   [44M,48M)  Kr [4096,512]
    //   [48M,52M)  Vr [4096,512]
    char* ws = (char*)d_ws;
    bf16* xb   = (bf16*)ws;
    bf16* Att  = xb;
    bf16* wT   = (bf16*)(ws + 16777216);
    bf16* wTq  = wT;
    bf16* wTk  = wT + (size_t)2048 * 2048;
    bf16* wTv  = wT + (size_t)2560 * 2048;
    bf16* woT  = wT;                                     // alias after QKV GEMM
    bf16* Vt_g = (bf16*)(ws + 25165824);                 // alias after QKV GEMM
    bf16* Qr   = (bf16*)(ws + 29360128);
    bf16* Kr   = (bf16*)(ws + 46137344);
    bf16* Vr   = (bf16*)(ws + 50331648);

    f2b_kernel<<<(M * CDIM / 4 + 255) / 256, 256, 0, stream>>>(x, xb, M * CDIM / 4);
    transpose_f2b_kernel<<<dim3((NH * HD) / 64, CDIM / 64), 256, 0, stream>>>(
        q_kernel, wTq, CDIM, NH * HD);
    transpose_f2b_kernel<<<dim3((NKV * HD) / 64, CDIM / 64), 256, 0, stream>>>(
        k_kernel, wTk, CDIM, NKV * HD);
    transpose_f2b_kernel<<<dim3((NKV * HD) / 64, CDIM / 64), 256, 0, stream>>>(
        v_kernel, wTv, CDIM, NKV * HD);

    // fused QKV projection -> compact Qr / Kr / Vr (768 blocks)
    gemm_qkv_kernel<<<dim3(NQKV / 128, M / 128), 256, 0, stream>>>(
        xb, wT, Qr, Kr, Vr, M, CDIM);

    // o_kernel transpose into woT (aliases wT -> must follow QKV GEMM)
    transpose_f2b_kernel<<<dim3(CDIM / 64, CDIM / 64), 256, 0, stream>>>(
        o_kernel, woT, CDIM, CDIM);

    // RoPE on compact Qr, Kr
    {
        int pairs_q = M * (NH * HD / 2);
        rope_kernel<<<pairs_q / 256, 256, 0, stream>>>(Qr, NH * HD, pairs_q);
        int pairs_k = M * (NKV * HD / 2);
        rope_kernel<<<pairs_k / 256, 256, 0, stream>>>(Kr, NKV * HD, pairs_k);
    }

    // V transpose (Vr -> Vt_g; Vt_g region free after QKV GEMM)
    vtrans_kernel<<<dim3((NKV * HD) / 64, SEQ / 64, BATCH), 256, 0, stream>>>(Vr, Vt_g);

    // flash attention (R8-validated): 64 q/block, grid (T/64, B*NH)
    attn_mfma4_kernel<<<dim3(SEQ / 64, BATCH * NH), 256, 0, stream>>>(
        Qr, Kr, Vt_g, Att);

    // output projection
    gemm_mfma_bt<float><<<dim3(CDIM / 128, M / 128), 256, 0, stream>>>(
        Att, woT, out, M, CDIM, CDIM);
}

// Round 11
// 400.734 us; speedup vs baseline: 1.3393x; 1.0543x over previous
//
#include <hip/hip_runtime.h>
#include <hip/hip_bf16.h>

typedef __hip_bfloat16 bf16;
typedef __attribute__((ext_vector_type(8))) short bf16x8;   // x32 MFMA A/B frag (4 VGPRs)
typedef __attribute__((ext_vector_type(4))) short bf16x4;   // x16 MFMA A/B frag (2 VGPRs)
typedef __attribute__((ext_vector_type(4))) float f32x4;    // MFMA C/D frag

// Problem constants (Attention_45681272160684)
#define BATCH 2
#define SEQ 2048
#define CDIM 2048
#define NH 16
#define NKV 4
#define HD 128
#define NQKV 3072   // fused projection width: 2048 Q | 512 K | 512 V

__device__ __forceinline__ float tof(float x)  { return x; }
__device__ __forceinline__ float tof(bf16 x)   { return __bfloat162float(x); }
__device__ __forceinline__ void  stf(float* p, float v) { *p = v; }
__device__ __forceinline__ void  stf(bf16* p,  float v) { *p = __float2bfloat16(v); }

__device__ __forceinline__ void gl_lds16(const bf16* g, bf16* l) {
    typedef const __attribute__((address_space(1))) unsigned int* gp_t;
    typedef __attribute__((address_space(3))) unsigned int* lp_t;
    __builtin_amdgcn_global_load_lds((gp_t)g, (lp_t)l, 16, 0, 0);
}

__device__ __forceinline__ f32x4 mfma16x16x16_bf16(bf16x4 a, bf16x4 b, f32x4 c) {
#if __has_builtin(__builtin_amdgcn_mfma_f32_16x16x16bf16_1k)
    return __builtin_amdgcn_mfma_f32_16x16x16bf16_1k(a, b, c, 0, 0, 0);
#else
    asm volatile("v_mfma_f32_16x16x16_bf16 %0, %1, %2, %0"
                 : "+v"(c) : "v"(a), "v"(b));
    return c;
#endif
}

__device__ __forceinline__ float fast_exp2(float x) {
#if __has_builtin(__builtin_amdgcn_exp2f)
    return __builtin_amdgcn_exp2f(x);
#else
    return exp2f(x);
#endif
}

// ---------------------------------------------------------------------------
// fp32 -> bf16 convert
// ---------------------------------------------------------------------------
__global__ __launch_bounds__(256) void f2b_kernel(const float* __restrict__ in,
                                                  bf16* __restrict__ out, int n4)
{
    int i = blockIdx.x * 256 + threadIdx.x;
    if (i >= n4) return;
    float4 v = *(const float4*)&in[(size_t)i * 4];
    bf16 o[4] = {__float2bfloat16(v.x), __float2bfloat16(v.y),
                 __float2bfloat16(v.z), __float2bfloat16(v.w)};
    *(ushort4*)&out[(size_t)i * 4] = *(ushort4*)o;
}

// ---------------------------------------------------------------------------
// Transposing convert: fp32 [R, Cn] -> bf16 [Cn, R]
// ---------------------------------------------------------------------------
__global__ __launch_bounds__(256) void transpose_f2b_kernel(
    const float* __restrict__ in, bf16* __restrict__ out, int R, int Cn)
{
    __shared__ float tile[64][65];
    const int r0 = blockIdx.y * 64, c0 = blockIdx.x * 64;
    for (int f = threadIdx.x; f < 4096; f += 256) {
        int r = f >> 6, c = f & 63;
        tile[r][c] = in[(size_t)(r0 + r) * Cn + c0 + c];
    }
    __syncthreads();
    for (int f = threadIdx.x; f < 4096; f += 256) {
        int r = f >> 6, c = f & 63;
        out[(size_t)(c0 + r) * R + r0 + c] = __float2bfloat16(tile[c][r]);
    }
}

// ---------------------------------------------------------------------------
// bf16 transpose per batch: Vr [B*SEQ, NKV*HD] -> Vt_g [(b*NKV+kvh)*HD + d][SEQ]
// ---------------------------------------------------------------------------
__global__ __launch_bounds__(256) void vtrans_kernel(
    const bf16* __restrict__ in, bf16* __restrict__ out)
{
    __shared__ bf16 tile[64][65];
    const int b = blockIdx.z;
    const int t0 = blockIdx.y * 64, c0 = blockIdx.x * 64;
    for (int f = threadIdx.x; f < 4096; f += 256) {
        int r = f >> 6, c = f & 63;
        tile[r][c] = in[(size_t)(b * SEQ + t0 + r) * (NKV * HD) + c0 + c];
    }
    __syncthreads();
    for (int f = threadIdx.x; f < 4096; f += 256) {
        int r = f >> 6, c = f & 63;
        out[(size_t)(b * NKV * HD + c0 + r) * SEQ + t0 + c] = tile[c][r];
    }
}

// ---------------------------------------------------------------------------
// Fused QKV MFMA GEMM with segment-remap epilogue (R10-validated).
// ---------------------------------------------------------------------------
__global__ __launch_bounds__(256) void gemm_qkv_kernel(
    const bf16* __restrict__ A, const bf16* __restrict__ Bt,
    bf16* __restrict__ Qr, bf16* __restrict__ Kr, bf16* __restrict__ Vr,
    int M, int K)
{
    __shared__ __align__(16) bf16 As[128 * 32];
    __shared__ __align__(16) bf16 Bs[128 * 32];

    const int tid = threadIdx.x;
    const int lane = tid & 63;
    const int wave = tid >> 6;
    const int m0 = blockIdx.y * 128;
    const int n0 = blockIdx.x * 128;
    const int wm = (wave >> 1) * 64;
    const int wn = (wave & 1) * 64;
    const int quad = lane >> 4;
    const int l16 = lane & 15;

    const int srow = tid >> 2;
    const int scol = (tid & 3) * 8;
    const bf16* Ag0 = A  + (size_t)(m0 + srow) * K + scol;
    const bf16* Ag1 = A  + (size_t)(m0 + srow + 64) * K + scol;
    const bf16* Bg0 = Bt + (size_t)(n0 + srow) * K + scol;
    const bf16* Bg1 = Bt + (size_t)(n0 + srow + 64) * K + scol;

    f32x4 acc[4][4];
#pragma unroll
    for (int mi = 0; mi < 4; ++mi)
#pragma unroll
        for (int ni = 0; ni < 4; ++ni)
            acc[mi][ni] = (f32x4){0.f, 0.f, 0.f, 0.f};

    for (int kt = 0; kt < K; kt += 32) {
        __syncthreads();
        gl_lds16(Ag0 + kt, &As[tid * 8]);
        gl_lds16(Ag1 + kt, &As[2048 + tid * 8]);
        gl_lds16(Bg0 + kt, &Bs[tid * 8]);
        gl_lds16(Bg1 + kt, &Bs[2048 + tid * 8]);
        __syncthreads();

        bf16x8 a[4], b[4];
#pragma unroll
        for (int mi = 0; mi < 4; ++mi)
            a[mi] = *(const bf16x8*)&As[(wm + mi * 16 + l16) * 32 + quad * 8];
#pragma unroll
        for (int ni = 0; ni < 4; ++ni)
            b[ni] = *(const bf16x8*)&Bs[(wn + ni * 16 + l16) * 32 + quad * 8];
#pragma unroll
        for (int mi = 0; mi < 4; ++mi)
#pragma unroll
            for (int ni = 0; ni < 4; ++ni)
                acc[mi][ni] = __builtin_amdgcn_mfma_f32_16x16x32_bf16(
                    a[mi], b[ni], acc[mi][ni], 0, 0, 0);
    }

    bf16* Cp; int Nst, cbase;
    if (n0 < 2048)      { Cp = Qr; Nst = 2048; cbase = n0; }
    else if (n0 < 2560) { Cp = Kr; Nst = 512;  cbase = n0 - 2048; }
    else                { Cp = Vr; Nst = 512;  cbase = n0 - 2560; }

#pragma unroll
    for (int mi = 0; mi < 4; ++mi)
#pragma unroll
        for (int ni = 0; ni < 4; ++ni) {
            int col = cbase + wn + ni * 16 + l16;
#pragma unroll
            for (int r = 0; r < 4; ++r) {
                int row = m0 + wm + mi * 16 + quad * 4 + r;
                Cp[(size_t)row * Nst + col] = __float2bfloat16(acc[mi][ni][r]);
            }
        }
}

// ---------------------------------------------------------------------------
// MFMA GEMM: C[M,N] = A[M,K] @ Bt[N,K]^T (m97 structure) — out-projection.
// ---------------------------------------------------------------------------
template <typename TC>
__global__ __launch_bounds__(256) void gemm_mfma_bt(
    const bf16* __restrict__ A, const bf16* __restrict__ Bt, TC* __restrict__ C,
    int M, int N, int K)
{
    __shared__ __align__(16) bf16 As[128 * 32];
    __shared__ __align__(16) bf16 Bs[128 * 32];

    const int tid = threadIdx.x;
    const int lane = tid & 63;
    const int wave = tid >> 6;
    const int m0 = blockIdx.y * 128;
    const int n0 = blockIdx.x * 128;
    const int wm = (wave >> 1) * 64;
    const int wn = (wave & 1) * 64;
    const int quad = lane >> 4;
    const int l16 = lane & 15;

    const int srow = tid >> 2;
    const int scol = (tid & 3) * 8;
    const bf16* Ag0 = A  + (size_t)(m0 + srow) * K + scol;
    const bf16* Ag1 = A  + (size_t)(m0 + srow + 64) * K + scol;
    const bf16* Bg0 = Bt + (size_t)(n0 + srow) * K + scol;
    const bf16* Bg1 = Bt + (size_t)(n0 + srow + 64) * K + scol;

    f32x4 acc[4][4];
#pragma unroll
    for (int mi = 0; mi < 4; ++mi)
#pragma unroll
        for (int ni = 0; ni < 4; ++ni)
            acc[mi][ni] = (f32x4){0.f, 0.f, 0.f, 0.f};

    for (int kt = 0; kt < K; kt += 32) {
        __syncthreads();
        gl_lds16(Ag0 + kt, &As[tid * 8]);
        gl_lds16(Ag1 + kt, &As[2048 + tid * 8]);
        gl_lds16(Bg0 + kt, &Bs[tid * 8]);
        gl_lds16(Bg1 + kt, &Bs[2048 + tid * 8]);
        __syncthreads();

        bf16x8 a[4], b[4];
#pragma unroll
        for (int mi = 0; mi < 4; ++mi)
            a[mi] = *(const bf16x8*)&As[(wm + mi * 16 + l16) * 32 + quad * 8];
#pragma unroll
        for (int ni = 0; ni < 4; ++ni)
            b[ni] = *(const bf16x8*)&Bs[(wn + ni * 16 + l16) * 32 + quad * 8];
#pragma unroll
        for (int mi = 0; mi < 4; ++mi)
#pragma unroll
            for (int ni = 0; ni < 4; ++ni)
                acc[mi][ni] = __builtin_amdgcn_mfma_f32_16x16x32_bf16(
                    a[mi], b[ni], acc[mi][ni], 0, 0, 0);
    }

#pragma unroll
    for (int mi = 0; mi < 4; ++mi)
#pragma unroll
        for (int ni = 0; ni < 4; ++ni) {
            int col = n0 + wn + ni * 16 + l16;
#pragma unroll
            for (int r = 0; r < 4; ++r) {
                int row = m0 + wm + mi * 16 + quad * 4 + r;
                stf(&C[(size_t)row * N + col], acc[mi][ni][r]);
            }
        }
}

// ---------------------------------------------------------------------------
// RoPE in place on [rows, ncols] bf16
// ---------------------------------------------------------------------------
__global__ __launch_bounds__(256) void rope_kernel(bf16* __restrict__ data,
                                                   int ncols, int total_pairs)
{
    int idx = blockIdx.x * 256 + threadIdx.x;
    if (idx >= total_pairs) return;
    int half = ncols >> 1;
    int row = idx / half;
    int p = idx - row * half;
    int head = p >> 6;
    int i = p & 63;
    int t = row & (SEQ - 1);
    float inv_ts = expf(-(float)i * 0.14391156831212787f);
    float angle = (float)t * inv_ts;
    float s, c;
    sincosf(angle, &s, &c);
    size_t base = (size_t)row * ncols + head * 128 + i;
    float x1 = __bfloat162float(data[base]);
    float x2 = __bfloat162float(data[base + 64]);
    data[base]      = __float2bfloat16(x1 * c - x2 * s);
    data[base + 64] = __float2bfloat16(x2 * c + x1 * s);
}

// ---------------------------------------------------------------------------
// GQA head-sharing LDS-staged register-transpose MFMA flash attention.
// Block = 4 waves = (2 q-heads sharing one kv-head) x (2 q-halves of 32).
// The R8 kw key-split becomes a sequential half loop inside each wave
// (identical per-half register liveness -> no spill), so each wave owns its
// complete O: NO cross-wave combine, no CB overlay, 1 barrier pair per tile.
// K/V staged once per block serves 2 heads -> staging + HBM fetch halved.
// ---------------------------------------------------------------------------
__global__ __launch_bounds__(256, 3) void attn_mfma5_kernel(
    const bf16* __restrict__ Q, const bf16* __restrict__ K,
    const bf16* __restrict__ Vt, bf16* __restrict__ Att)
{
    __shared__ __align__(16) char smem[32768];       // Ks 16K | Vts 16K
    bf16* Ks  = (bf16*)smem;                         // [64 key][128 d] chunk-swizzled
    bf16* Vts = (bf16*)(smem + 16384);               // [128 d][64 key] chunk-swizzled

    const int tid = threadIdx.x;
    const int lane = tid & 63;
    const int w = tid >> 6;
    const int hs = w >> 1;            // head select within the pair
    const int qw = w & 1;             // q half (32 q each)
    const int quad = lane >> 4;
    const int l16 = lane & 15;
    const int bh = blockIdx.y;        // [b:1][kvh:2][pair:1]
    const int b   = bh >> 3;
    const int kvh = (bh >> 1) & 3;
    const int pr  = bh & 1;
    const int hq  = kvh + 4 * (pr * 2 + hs);         // hq & 3 == kvh  ✓
    const int qt = (gridDim.x - 1) - blockIdx.x;     // heavy-first
    const int q0 = qt * 64 + qw * 32;                // wave's q rows: q0 + g*16 + l16

    // Q^T B-frags (x32): two 16-q column groups
    bf16x8 qf[2][4];
#pragma unroll
    for (int g = 0; g < 2; ++g) {
        size_t qrow = (size_t)(b * SEQ + q0 + g * 16 + l16) * (NH * HD) + hq * HD;
#pragma unroll
        for (int kk = 0; kk < 4; ++kk)
            qf[g][kk] = *(const bf16x8*)&Q[qrow + kk * 32 + quad * 8];
    }

    const bf16* Kb = K  + (size_t)(b * SEQ) * (NKV * HD) + kvh * HD;  // row 512 elems
    const bf16* Vb = Vt + (size_t)((b * NKV + kvh) * HD) * SEQ;       // row 2048 elems

    f32x4 O[2][8];   // complete O^T for this wave: row=d=dj*16+quad*4+r, col=q
#pragma unroll
    for (int g = 0; g < 2; ++g)
#pragma unroll
        for (int dj = 0; dj < 8; ++dj) O[g][dj] = (f32x4){0.f, 0.f, 0.f, 0.f};
    float lsum[2] = {0.f, 0.f};

    // staging index precompute (linear-in-tid LDS dest; XOR swizzle in source)
    const int srowK = tid >> 4;                 // key-within-16-group
    const int sgcK  = (tid & 15) ^ srowK;       // swizzled d-chunk
    const int srowV = tid >> 3;                 // d-within-32-group
    const int sgcV  = (tid & 7) ^ (srowV & 7);  // swizzled key-chunk

    const int ntiles = qt + 1;
    for (int jt = 0; jt < ntiles; ++jt) {
        const int j0 = jt * 64;
        __syncthreads();   // previous tile's readers done
#pragma unroll
        for (int c = 0; c < 4; ++c) {
            gl_lds16(Kb + (size_t)(j0 + c * 16 + srowK) * (NKV * HD) + sgcK * 8,
                     Ks + c * 2048 + tid * 8);
            gl_lds16(Vb + (size_t)(c * 32 + srowV) * SEQ + j0 + sgcV * 8,
                     Vts + c * 2048 + tid * 8);
        }
        __syncthreads();   // vmcnt drained, tiles visible

        const bool diag = (jt == qt);
#pragma unroll
        for (int half = 0; half < 2; ++half) {
            // ---- S^T[32 key][32 q]: A=K frags (swizzle-read), B=Q^T regs ----
            f32x4 sacc[2][2];
#pragma unroll
            for (int mt = 0; mt < 2; ++mt) {
#pragma unroll
                for (int g = 0; g < 2; ++g) sacc[mt][g] = (f32x4){0.f, 0.f, 0.f, 0.f};
                const int krow = (half * 32 + mt * 16 + l16) * 128;
#pragma unroll
                for (int kk = 0; kk < 4; ++kk) {
                    bf16x8 kf = *(const bf16x8*)&Ks[krow + (((kk * 4 + quad) ^ l16) * 8)];
#pragma unroll
                    for (int g = 0; g < 2; ++g)
                        sacc[mt][g] = __builtin_amdgcn_mfma_f32_16x16x32_bf16(
                            kf, qf[g][kk], sacc[mt][g], 0, 0, 0);
                }
            }

            // ---- softcap (Pade, exp2-folded) + mask -> P^T frags (registers) ----
            bf16x4 pf[2][2];
#pragma unroll
            for (int mt = 0; mt < 2; ++mt)
#pragma unroll
                for (int g = 0; g < 2; ++g) {
                    bf16 pb[4];
#pragma unroll
                    for (int r = 0; r < 4; ++r) {
                        float u = sacc[mt][g][r];
                        float t2 = u * u;
                        float num = fmaf(t2, 9.96274e-4f, 8607.814f);
                        float den = fmaf(t2, 0.0703125f, 67500.f);
                        float s2 = u * num * __builtin_amdgcn_rcpf(den);
                        float p = fast_exp2(s2);   // exp(50*tanh(u/(sqrt(128)*50)))
                        if (diag) {
                            int kl = half * 32 + mt * 16 + quad * 4 + r;
                            int ql = qw * 32 + g * 16 + l16;
                            p = (kl <= ql) ? p : 0.f;
                        }
                        lsum[g] += p;
                        pb[r] = __float2bfloat16(p);
                    }
                    pf[mt][g] = *(bf16x4*)pb;
                }

            // ---- O^T += V^T @ P^T (x16; V^T frags from swizzled LDS) ----
#pragma unroll
            for (int dj = 0; dj < 8; ++dj) {
                const int vrow = (dj * 16 + l16) * 64;
                const int dl7 = l16 & 7;
#pragma unroll
                for (int mt = 0; mt < 2; ++mt) {
                    int c16 = half * 4 + mt * 2 + (quad >> 1);
                    bf16x4 vf = *(const bf16x4*)&Vts[vrow + ((c16 ^ dl7) << 3)
                                                     + (quad & 1) * 4];
#pragma unroll
                    for (int g = 0; g < 2; ++g)
                        O[g][dj] = mfma16x16x16_bf16(vf, pf[mt][g], O[g][dj]);
                }
            }
        }
    }

    // ---- epilogue: per-wave l totals (sum across quads), normalize, store ----
#pragma unroll
    for (int g = 0; g < 2; ++g) {
        float v = lsum[g];
        v += __shfl_xor(v, 16);
        v += __shfl_xor(v, 32);
        float inv = 1.f / v;
        size_t obase = (size_t)(b * SEQ + q0 + g * 16 + l16) * (NH * HD) + hq * HD;
#pragma unroll
        for (int dj = 0; dj < 8; ++dj) {
            bf16 ob[4];
#pragma unroll
            for (int r = 0; r < 4; ++r)
                ob[r] = __float2bfloat16(O[g][dj][r] * inv);
            *(ushort4*)&Att[obase + dj * 16 + quad * 4] = *(ushort4*)ob;
        }
    }
}

// ---------------------------------------------------------------------------
extern "C" void kernel_launch(void* const* d_in, const int* in_sizes, int n_in,
                              void* d_out, int out_size, void* d_ws, size_t ws_size,
                              hipStream_t stream) {
    const float* x        = (const float*)d_in[0];
    // d_in[1] = mask: deterministic causal tril -> not read
    const float* q_kernel = (const float*)d_in[2];
    const float* k_kernel = (const float*)d_in[3];
    const float* v_kernel = (const float*)d_in[4];
    const float* o_kernel = (const float*)d_in[5];
    float* out = (float*)d_out;

    const int M = BATCH * SEQ;       // 4096
    // workspace (52 MB): same layout as R10 (validated)
    char* ws = (char*)d_ws;
    bf16* xb   = (bf16*)ws;
    bf16* Att  = xb;
    bf16* wT   = (bf16*)(ws + 16777216);
    bf16* wTq  = wT;
    bf16* wTk  = wT + (size_t)2048 * 2048;
    bf16* wTv  = wT + (size_t)2560 * 2048;
    bf16* woT  = wT;                                     // alias after QKV GEMM
    bf16* Vt_g = (bf16*)(ws + 25165824);                 // alias after QKV GEMM
    bf16* Qr   = (bf16*)(ws + 29360128);
    bf16* Kr   = (bf16*)(ws + 46137344);
    bf16* Vr   = (bf16*)(ws + 50331648);

    f2b_kernel<<<(M * CDIM / 4 + 255) / 256, 256, 0, stream>>>(x, xb, M * CDIM / 4);
    transpose_f2b_kernel<<<dim3((NH * HD) / 64, CDIM / 64), 256, 0, stream>>>(
        q_kernel, wTq, CDIM, NH * HD);
    transpose_f2b_kernel<<<dim3((NKV * HD) / 64, CDIM / 64), 256, 0, stream>>>(
        k_kernel, wTk, CDIM, NKV * HD);
    transpose_f2b_kernel<<<dim3((NKV * HD) / 64, CDIM / 64), 256, 0, stream>>>(
        v_kernel, wTv, CDIM, NKV * HD);

    // fused QKV projection -> compact Qr / Kr / Vr (768 blocks)
    gemm_qkv_kernel<<<dim3(NQKV / 128, M / 128), 256, 0, stream>>>(
        xb, wT, Qr, Kr, Vr, M, CDIM);

    // o_kernel transpose into woT (aliases wT -> must follow QKV GEMM)
    transpose_f2b_kernel<<<dim3(CDIM / 64, CDIM / 64), 256, 0, stream>>>(
        o_kernel, woT, CDIM, CDIM);

    // RoPE on compact Qr, Kr
    {
        int pairs_q = M * (NH * HD / 2);
        rope_kernel<<<pairs_q / 256, 256, 0, stream>>>(Qr, NH * HD, pairs_q);
        int pairs_k = M * (NKV * HD / 2);
        rope_kernel<<<pairs_k / 256, 256, 0, stream>>>(Kr, NKV * HD, pairs_k);
    }

    // V transpose (Vr -> Vt_g)
    vtrans_kernel<<<dim3((NKV * HD) / 64, SEQ / 64, BATCH), 256, 0, stream>>>(Vr, Vt_g);

    // GQA head-sharing flash attention: 64 q x 2 heads per block,
    // grid (T/64, B*NKV*2) = (32, 16)
    attn_mfma5_kernel<<<dim3(SEQ / 64, BATCH * NKV * 2), 256, 0, stream>>>(
        Qr, Kr, Vt_g, Att);

    // output projection
    gemm_mfma_bt<float><<<dim3(CDIM / 128, M / 128), 256, 0, stream>>>(
        Att, woT, out, M, CDIM, CDIM);
}